// Round 3
// baseline (174.869 us; speedup 1.0000x reference)
//
#include <hip/hip_runtime.h>
#include <hip/hip_bf16.h>

// ColorHistogramLoss — windowed soft histogram, LDS-atomic accumulation.
//
// Key facts (post-mortem R2): acc[64] register histograms spill to scratch
// (VGPR_Count=64, VALUBusy=11%) -> both prior rounds were scratch-bound.
// In fp32 the Gaussian weight exp(-d^2/2) is < 3e-7 beyond |d|=5.5 bins;
// dropping those changes the final CDF loss by ~4e-9 << 2.7e-5 threshold.
// So: per pixel evaluate only a 12-bin window around t = x*64.
//
// Window eval: anchor at bin floor(t) (weight in [e^-0.125, 1]), then a
// geometric chain outward: w_{k+1}/w_k = e^{d_k - 0.5}, successive ratios
// decay by e^-1. 3 exps + 2 muls/bin; all intermediates in [tiny, 1] --
// no overflow even at the clamped image edges (monotone toward t).
// Accumulate with ds_add_f32 LDS atomics into a per-block 64-bin hist
// (dynamic bin index -> LDS, not registers). ~30 VGPRs, no spill.
//
// Launches: tiny hipMemsetAsync (zero 24*64 hist + counter) + one kernel;
// last-arriving block (agent-scope ACQ_REL counter) runs scan/cdf/mean tail.

#define BINS 64
#define NCH 12            // B*C
#define HW 65536          // 256*256
#define BPC 32            // blocks per channel-image
#define NBLK (2 * NCH * BPC)                   // 768
#define PIX_PER_BLOCK (HW / BPC)               // 2048
#define THREADS 256

#define LOG2E   1.4426950408889634f
#define LOG2E_H 0.7213475204444817f
#define E1C     0.36787944117144233f   // e^-1

__device__ __forceinline__ float fast_exp2(float x) {
#if __has_builtin(__builtin_amdgcn_exp2f)
    return __builtin_amdgcn_exp2f(x);
#else
    return exp2f(x);
#endif
}

__device__ __forceinline__ void eval_pixel(float t, float* __restrict__ lh) {
    // window bins j0..j0+11, anchor at k=6 (= bin floor(t) when unclamped)
    int j0 = (int)floorf(t) - 6;
    j0 = j0 < 0 ? 0 : (j0 > BINS - 12 ? BINS - 12 : j0);
    float u  = t - (float)j0 - 6.5f;                 // distance at anchor
    float wc = fast_exp2(-(u * u) * LOG2E_H);        // e^{-u^2/2}
    float ru = fast_exp2(fmaf(u,  LOG2E, -0.5f * LOG2E));  // e^{u-0.5}
    float rd = fast_exp2(fmaf(-u, LOG2E, -0.5f * LOG2E));  // e^{-u-0.5}
    float* lp = lh + j0;
    atomicAdd(&lp[6], wc);
    float q = wc, r = ru;
    #pragma unroll
    for (int k = 7; k < 12; ++k) {                   // upward chain
        q *= r; atomicAdd(&lp[k], q); r *= E1C;
    }
    q = wc; r = rd;
    #pragma unroll
    for (int k = 5; k >= 0; --k) {                   // downward chain
        q *= r; atomicAdd(&lp[k], q); r *= E1C;
    }
}

__global__ __launch_bounds__(THREADS) void fused_kernel(
        const float* __restrict__ pred,
        const float* __restrict__ target,
        float* __restrict__ hist,           // ws: 24*64 floats, pre-zeroed
        unsigned int* __restrict__ counter, // ws: 1 uint, pre-zeroed
        float* __restrict__ out) {
    const int blk   = blockIdx.x;
    const int ch    = blk / BPC;            // 0..23
    const int chunk = blk % BPC;
    const float* src = (ch < NCH) ? (pred + (size_t)ch * HW)
                                  : (target + (size_t)(ch - NCH) * HW);
    const float4* src4 = (const float4*)(src + chunk * PIX_PER_BLOCK);

    __shared__ float lh[BINS];
    __shared__ int is_last;
    if (threadIdx.x < BINS) lh[threadIdx.x] = 0.0f;
    __syncthreads();

    #pragma unroll
    for (int i = 0; i < PIX_PER_BLOCK / (4 * THREADS); ++i) {   // 2 iters
        float4 v = src4[threadIdx.x + i * THREADS];
        eval_pixel(v.x * 64.0f, lh);
        eval_pixel(v.y * 64.0f, lh);
        eval_pixel(v.z * 64.0f, lh);
        eval_pixel(v.w * 64.0f, lh);
    }

    __syncthreads();
    if (threadIdx.x < BINS)
        atomicAdd(&hist[ch * BINS + threadIdx.x], lh[threadIdx.x]);

    // block-completion counter (release our atomics, acquire others')
    __threadfence();
    if (threadIdx.x == 0) {
        unsigned prev = __hip_atomic_fetch_add(counter, 1u, __ATOMIC_ACQ_REL,
                                               __HIP_MEMORY_SCOPE_AGENT);
        is_last = (prev == NBLK - 1);
    }
    __syncthreads();
    if (!is_last) return;

    // ---- tail: scan/cdf/|diff|/mean, one block (4 waves) ----
    const int lane = threadIdx.x & 63;
    const int w    = threadIdx.x >> 6;
    float local = 0.0f;
    for (int pch = w; pch < NCH; pch += 4) {
        float ps = hist[pch * BINS + lane];
        float ts = hist[(NCH + pch) * BINS + lane];
        #pragma unroll
        for (int d = 1; d < 64; d <<= 1) {
            float a = __shfl_up(ps, d, 64);
            float b = __shfl_up(ts, d, 64);
            if (lane >= d) { ps += a; ts += b; }
        }
        float ptot = __shfl(ps, 63, 64);
        float ttot = __shfl(ts, 63, 64);
        float dv = fabsf(ps / (ptot + 1e-8f) - ts / (ttot + 1e-8f));
        #pragma unroll
        for (int k = 32; k >= 1; k >>= 1) dv += __shfl_xor(dv, k, 64);
        local += dv;
    }
    __shared__ float wsum[4];
    if (lane == 0) wsum[w] = local;
    __syncthreads();
    if (threadIdx.x == 0)
        out[0] = (wsum[0] + wsum[1] + wsum[2] + wsum[3]) * (1.0f / (NCH * BINS));
}

extern "C" void kernel_launch(void* const* d_in, const int* in_sizes, int n_in,
                              void* d_out, int out_size, void* d_ws, size_t ws_size,
                              hipStream_t stream) {
    const float* pred   = (const float*)d_in[0];
    const float* target = (const float*)d_in[1];
    float* hist = (float*)d_ws;                      // 24*64 floats
    unsigned int* counter = (unsigned int*)((char*)d_ws + NCH * 2 * BINS * 4);
    float* out = (float*)d_out;

    hipMemsetAsync(d_ws, 0, NCH * 2 * BINS * 4 + 4, stream);
    fused_kernel<<<dim3(NBLK), dim3(THREADS), 0, stream>>>(
        pred, target, hist, counter, out);
}

// Round 4
// 133.270 us; speedup vs baseline: 1.3121x; 1.3121x over previous
//
#include <hip/hip_runtime.h>
#include <hip/hip_bf16.h>

// ColorHistogramLoss — windowed soft histogram, per-thread PRIVATE LDS
// column histograms (no atomics).
//
// Post-mortem R3: LDS atomicAdd with divergent lane addresses costs ~245
// cyc/wave-instruction (micro-serialized per lane) -> 118 us, VALUBusy 1.3%.
// Fix: privatize. lh[bin][tid] with 128 threads: addr = bin*128+tid, bank =
// tid%32 for all lanes -> conflict-free for ANY bin pattern; each thread owns
// a column -> plain ds_read/v_add/ds_write RMW (DS ops are in-order per wave,
// so same-address RMW across pixels is correct without fences).
//
// Window math (unchanged from R3, passed): weights beyond |d|=5.5 bins are
// < 3e-7 -> 12-bin window around t=x*64. Anchor at nearest-bin (weight in
// [e^-0.125,1]), geometric chain outward: 3 exps + 2 muls/bin.
// All intermediates <= max(1, e^6) -- no overflow (chain values are exact
// Gaussian weights <= 1; ratio r <= e^6 at clamped edges).
//
// Launches: hipMemsetAsync (zero 24*64 hist + counter, 1540 B) + one kernel;
// last-arriving block (agent-scope ACQ_REL counter) runs scan/cdf/mean tail.

#define BINS 64
#define NCH 12            // B*C
#define HW 65536          // 256*256
#define THREADS 128
#define PPT 8             // pixels per thread
#define PXB (THREADS * PPT)                 // 1024 pixels per block
#define BPC (HW / PXB)                      // 64 blocks per channel-image
#define NBLK (2 * NCH * BPC)                // 1536

#define LOG2E   1.4426950408889634f
#define LOG2E_H 0.7213475204444817f
#define E1C     0.36787944117144233f   // e^-1

__device__ __forceinline__ float fast_exp2(float x) {
#if __has_builtin(__builtin_amdgcn_exp2f)
    return __builtin_amdgcn_exp2f(x);
#else
    return exp2f(x);
#endif
}

__device__ __forceinline__ void eval_pixel(float t, float* __restrict__ col) {
    // window bins j0..j0+11, anchor at k=6
    int j0 = (int)floorf(t) - 6;
    j0 = j0 < 0 ? 0 : (j0 > BINS - 12 ? BINS - 12 : j0);
    float u  = t - (float)j0 - 6.5f;
    float wc = fast_exp2(-(u * u) * LOG2E_H);              // e^{-u^2/2}
    float ru = fast_exp2(fmaf(u,  LOG2E, -0.5f * LOG2E));  // e^{u-0.5}
    float rd = fast_exp2(fmaf(-u, LOG2E, -0.5f * LOG2E));  // e^{-u-0.5}

    float w[12];
    w[6] = wc;
    float q = wc, r = ru;
    #pragma unroll
    for (int k = 7; k < 12; ++k) { q *= r; w[k] = q; r *= E1C; }
    q = wc; r = rd;
    #pragma unroll
    for (int k = 5; k >= 0; --k) { q *= r; w[k] = q; r *= E1C; }

    float* p = col + j0 * THREADS;
    float old[12];
    #pragma unroll
    for (int k = 0; k < 12; ++k) old[k] = p[k * THREADS];   // batch reads
    #pragma unroll
    for (int k = 0; k < 12; ++k) p[k * THREADS] = old[k] + w[k];
}

__global__ __launch_bounds__(THREADS) void fused_kernel(
        const float* __restrict__ pred,
        const float* __restrict__ target,
        float* __restrict__ hist,           // ws: 24*64 floats, pre-zeroed
        unsigned int* __restrict__ counter, // ws: 1 uint, pre-zeroed
        float* __restrict__ out) {
    const int tid   = threadIdx.x;
    const int blk   = blockIdx.x;
    const int ch    = blk / BPC;            // 0..23
    const int chunk = blk % BPC;
    const float* src = (ch < NCH) ? (pred + (size_t)ch * HW)
                                  : (target + (size_t)(ch - NCH) * HW);
    const float4* src4 = (const float4*)(src + chunk * PXB);

    __shared__ float lh[BINS * THREADS];    // 32 KB, [bin][tid]
    __shared__ float half1[BINS];
    __shared__ int is_last;

    // zero private histograms (vectorized)
    float4* lh4 = (float4*)lh;
    #pragma unroll
    for (int i = 0; i < (BINS * THREADS / 4) / THREADS; ++i)   // 16 iters
        lh4[tid + i * THREADS] = make_float4(0.f, 0.f, 0.f, 0.f);
    __syncthreads();

    float* col = lh + tid;
    #pragma unroll
    for (int i = 0; i < PPT / 4; ++i) {     // 2 iters
        float4 v = src4[tid + i * THREADS];
        eval_pixel(v.x * 64.0f, col);
        eval_pixel(v.y * 64.0f, col);
        eval_pixel(v.z * 64.0f, col);
        eval_pixel(v.w * 64.0f, col);
    }
    __syncthreads();

    // per-bin reduction: thread (b,h) sums half h of bin b's row.
    // diagonal t-order keeps lanes 2-way-per-bank (free).
    const int b = tid & 63;
    const int h = tid >> 6;
    float s = 0.0f;
    for (int i = 0; i < 64; ++i) {
        int t = h * 64 + ((b + i) & 63);
        s += lh[b * THREADS + t];
    }
    if (h == 1) half1[b] = s;
    __syncthreads();
    if (h == 0) atomicAdd(&hist[ch * BINS + b], s + half1[b]);

    // block-completion counter (release our atomics, acquire others')
    __threadfence();
    if (tid == 0) {
        unsigned prev = __hip_atomic_fetch_add(counter, 1u, __ATOMIC_ACQ_REL,
                                               __HIP_MEMORY_SCOPE_AGENT);
        is_last = (prev == NBLK - 1);
    }
    __syncthreads();
    if (!is_last) return;

    // ---- tail: scan/cdf/|diff|/mean, this block (2 waves) ----
    const int lane = tid & 63;
    const int w    = tid >> 6;
    float local = 0.0f;
    for (int pch = w; pch < NCH; pch += 2) {
        float ps = hist[pch * BINS + lane];
        float ts = hist[(NCH + pch) * BINS + lane];
        #pragma unroll
        for (int d = 1; d < 64; d <<= 1) {
            float a = __shfl_up(ps, d, 64);
            float bv = __shfl_up(ts, d, 64);
            if (lane >= d) { ps += a; ts += bv; }
        }
        float ptot = __shfl(ps, 63, 64);
        float ttot = __shfl(ts, 63, 64);
        float dv = fabsf(ps / (ptot + 1e-8f) - ts / (ttot + 1e-8f));
        #pragma unroll
        for (int k = 32; k >= 1; k >>= 1) dv += __shfl_xor(dv, k, 64);
        local += dv;
    }
    __shared__ float wsum[2];
    if (lane == 0) wsum[w] = local;
    __syncthreads();
    if (tid == 0)
        out[0] = (wsum[0] + wsum[1]) * (1.0f / (NCH * BINS));
}

extern "C" void kernel_launch(void* const* d_in, const int* in_sizes, int n_in,
                              void* d_out, int out_size, void* d_ws, size_t ws_size,
                              hipStream_t stream) {
    const float* pred   = (const float*)d_in[0];
    const float* target = (const float*)d_in[1];
    float* hist = (float*)d_ws;                      // 24*64 floats
    unsigned int* counter = (unsigned int*)((char*)d_ws + NCH * 2 * BINS * 4);
    float* out = (float*)d_out;

    hipMemsetAsync(d_ws, 0, NCH * 2 * BINS * 4 + 4, stream);
    fused_kernel<<<dim3(NBLK), dim3(THREADS), 0, stream>>>(
        pred, target, hist, counter, out);
}

// Round 5
// 119.410 us; speedup vs baseline: 1.4644x; 1.1161x over previous
//
#include <hip/hip_runtime.h>
#include <hip/hip_bf16.h>

// ColorHistogramLoss — register-accumulator soft histogram (R2 structure)
// with the VGPR occupancy-cap fixed.
//
// Post-mortem history:
//  R2: acc[64] in registers + power-form eval, __launch_bounds__(256) ->
//      backend targets max occupancy, caps VGPR at 64, SPILLS acc to scratch
//      -> 73 us, VALUBusy 11%. Math verified (absmax 0.0).
//  R3: LDS atomics: ~245 cyc per divergent ds-atomic -> 118 us.
//  R4: private LDS columns: 32KB/block -> 2 waves/SIMD, ds-latency-bound
//      (57 cyc/LDS-op) -> 78 us, VALUBusy 3.8%.
// Fix here: __launch_bounds__(THREADS, 2) lifts the VGPR cap to 256 ->
// acc[64] + temps (~110 VGPR) live entirely in registers. Hot loop is pure
// VALU: per 8-bin segment 2 exps + ~24 cheap ops (power-form Gaussian:
// w_{b+k} = w0 * m^k * e^{-k(k-1)/2}, m = e^{u-0.5}; u clamped to 13 so the
// dead far-tail gives 0*finite, never 0*inf).
//
// Launches: hipMemsetAsync (zero 24*64 hist + counter, 1540 B) + one kernel;
// wave butterfly transpose-reduce -> LDS combine (4 waves) -> global atomic;
// last-arriving block (agent-scope ACQ_REL counter) runs scan/cdf/mean tail.

#define BINS 64
#define NCH 12            // B*C
#define HW 65536          // 256*256
#define THREADS 256
#define PPT 8             // pixels per thread
#define PXB (THREADS * PPT)                 // 2048
#define BPC (HW / PXB)                      // 32 blocks per channel-image
#define NBLK (2 * NCH * BPC)                // 768

// K_k = e^{-k(k-1)/2}
#define K2 0.36787944117144233f
#define K3 0.049787068367863944f
#define K4 0.0024787521766663585f
#define K5 4.5399929762484854e-05f
#define K6 3.059023205018258e-07f
#define K7 7.582560427911907e-10f
#define LOG2E   1.4426950408889634f
#define LOG2E_H 0.7213475204444817f

__device__ __forceinline__ float fast_exp2(float x) {
#if __has_builtin(__builtin_amdgcn_exp2f)
    return __builtin_amdgcn_exp2f(x);
#else
    return exp2f(x);
#endif
}

__device__ __forceinline__ void eval_pixel(float t, float* __restrict__ acc) {
    #pragma unroll
    for (int s = 0; s < 8; ++s) {
        float u  = t - ((float)(8 * s) + 0.5f);
        float um = fminf(u, 13.0f);
        float w0 = fast_exp2(-(u * u) * LOG2E_H);             // e^{-u^2/2}
        float m  = fast_exp2(fmaf(um, LOG2E, -0.5f * LOG2E)); // e^{um-0.5}
        float m2 = m * m;
        float m3 = m2 * m;
        float m4 = m2 * m2;
        float m5 = m3 * m2;
        float m6 = m3 * m3;
        float m7 = m4 * m3;
        acc[8 * s + 0] += w0;
        acc[8 * s + 1] = fmaf(w0, m, acc[8 * s + 1]);
        acc[8 * s + 2] = fmaf(w0 * K2, m2, acc[8 * s + 2]);
        acc[8 * s + 3] = fmaf(w0 * K3, m3, acc[8 * s + 3]);
        acc[8 * s + 4] = fmaf(w0 * K4, m4, acc[8 * s + 4]);
        acc[8 * s + 5] = fmaf(w0 * K5, m5, acc[8 * s + 5]);
        acc[8 * s + 6] = fmaf(w0 * K6, m6, acc[8 * s + 6]);
        acc[8 * s + 7] = fmaf(w0 * K7, m7, acc[8 * s + 7]);
    }
}

__global__ __launch_bounds__(THREADS, 2) void fused_kernel(
        const float* __restrict__ pred,
        const float* __restrict__ target,
        float* __restrict__ hist,           // ws: 24*64 floats, pre-zeroed
        unsigned int* __restrict__ counter, // ws: 1 uint, pre-zeroed
        float* __restrict__ out) {
    const int tid   = threadIdx.x;
    const int blk   = blockIdx.x;
    const int ch    = blk / BPC;            // 0..23
    const int chunk = blk % BPC;
    const float* src = (ch < NCH) ? (pred + (size_t)ch * HW)
                                  : (target + (size_t)(ch - NCH) * HW);
    const float4* src4 = (const float4*)(src + chunk * PXB);

    float acc[BINS];
    #pragma unroll
    for (int j = 0; j < BINS; ++j) acc[j] = 0.0f;

    #pragma unroll
    for (int i = 0; i < PPT / 4; ++i) {     // 2 x float4
        float4 v = src4[tid + i * THREADS];
        eval_pixel(v.x * 64.0f, acc);
        eval_pixel(v.y * 64.0f, acc);
        eval_pixel(v.z * 64.0f, acc);
        eval_pixel(v.w * 64.0f, acc);
    }

    // Wave butterfly transpose-reduce: lane l ends with sum over lanes of acc[l]
    const int lane = tid & 63;
    #pragma unroll
    for (int k = 32; k >= 1; k >>= 1) {
        const bool hi = (lane & k) != 0;
        #pragma unroll
        for (int i = 0; i < k; ++i) {
            float keepv = hi ? acc[i + k] : acc[i];
            float sendv = hi ? acc[i] : acc[i + k];
            acc[i] = keepv + __shfl_xor(sendv, k, 64);
        }
    }
    float wave_sum = acc[0];

    // Combine the block's 4 waves in LDS, then one global atomic per bin.
    __shared__ float bh[BINS];
    __shared__ int is_last;
    if (tid < BINS) bh[tid] = 0.0f;
    __syncthreads();
    atomicAdd(&bh[lane], wave_sum);         // 64 distinct banks/addrs per wave
    __syncthreads();
    if (tid < BINS)
        atomicAdd(&hist[ch * BINS + tid], bh[tid]);

    // block-completion counter (release our atomics, acquire others')
    __threadfence();
    if (tid == 0) {
        unsigned prev = __hip_atomic_fetch_add(counter, 1u, __ATOMIC_ACQ_REL,
                                               __HIP_MEMORY_SCOPE_AGENT);
        is_last = (prev == NBLK - 1);
    }
    __syncthreads();
    if (!is_last) return;

    // ---- tail: scan/cdf/|diff|/mean, this block (4 waves) ----
    const int w = tid >> 6;
    float local = 0.0f;
    for (int pch = w; pch < NCH; pch += 4) {
        float ps = hist[pch * BINS + lane];
        float ts = hist[(NCH + pch) * BINS + lane];
        #pragma unroll
        for (int d = 1; d < 64; d <<= 1) {
            float a = __shfl_up(ps, d, 64);
            float b = __shfl_up(ts, d, 64);
            if (lane >= d) { ps += a; ts += b; }
        }
        float ptot = __shfl(ps, 63, 64);
        float ttot = __shfl(ts, 63, 64);
        float dv = fabsf(ps / (ptot + 1e-8f) - ts / (ttot + 1e-8f));
        #pragma unroll
        for (int k = 32; k >= 1; k >>= 1) dv += __shfl_xor(dv, k, 64);
        local += dv;
    }
    __shared__ float wsum[4];
    if (lane == 0) wsum[w] = local;
    __syncthreads();
    if (tid == 0)
        out[0] = (wsum[0] + wsum[1] + wsum[2] + wsum[3]) * (1.0f / (NCH * BINS));
}

extern "C" void kernel_launch(void* const* d_in, const int* in_sizes, int n_in,
                              void* d_out, int out_size, void* d_ws, size_t ws_size,
                              hipStream_t stream) {
    const float* pred   = (const float*)d_in[0];
    const float* target = (const float*)d_in[1];
    float* hist = (float*)d_ws;                      // 24*64 floats
    unsigned int* counter = (unsigned int*)((char*)d_ws + NCH * 2 * BINS * 4);
    float* out = (float*)d_out;

    hipMemsetAsync(d_ws, 0, NCH * 2 * BINS * 4 + 4, stream);
    fused_kernel<<<dim3(NBLK), dim3(THREADS), 0, stream>>>(
        pred, target, hist, counter, out);
}